// Round 10
// baseline (328.502 us; speedup 1.0000x reference)
//
#include <hip/hip_runtime.h>
#include <hip/hip_bf16.h>

#define N 4096
#define F 256
#define P 5
#define EPSV 1e-8f
#define BK 32
#define NSTEP (F / BK)  // 8
#define NTRI 2080       // 64*65/2 upper-triangle 64x64 tiles
#define GRIDSZ 512      // persistent blocks

typedef __attribute__((ext_vector_type(8))) short bf16x8;
typedef __attribute__((ext_vector_type(4))) float f32x4;

__device__ __forceinline__ f32x4 mfma16(bf16x8 a, bf16x8 b, f32x4 c) {
    return __builtin_amdgcn_mfma_f32_16x16x32_bf16(a, b, c, 0, 0, 0);
}

__device__ __forceinline__ void gload16(const void* src, const char* ldsdst) {
    __builtin_amdgcn_global_load_lds(
        (const __attribute__((address_space(1))) void*)src,
        (__attribute__((address_space(3))) void*)ldsdst, 16, 0, 0);
}

// K0 (fused): msg = E @ A via sparse index compaction, norms, bf16 casts,
// per-(agent,persona) float4 table {alpha, beta, p, p+delta} (AoS by agent),
// per-persona consts; also resets the gram work-stealing counter.
__global__ __launch_bounds__(256, 8) void prep_kernel(
    const float* __restrict__ E, const float* __restrict__ A,
    const float* __restrict__ persona,
    const float* __restrict__ Tt, const float* __restrict__ ee,
    const float* __restrict__ rr, const float* __restrict__ Ww,
    const int* __restrict__ times,
    __hip_bfloat16* __restrict__ Abf, __hip_bfloat16* __restrict__ Mbf,
    float4* __restrict__ qtab, float* __restrict__ cst, int* __restrict__ ctr) {
    __shared__ int cnt;
    __shared__ int list[1024];
    const int a = blockIdx.x;
    const int t = threadIdx.x;
    if (t == 0) cnt = 0;
    __syncthreads();
    const float4* erow = (const float4*)(E + (size_t)a * N);
    for (int b = t; b < N / 4; b += 256) {
        const float4 v = erow[b];
        if (v.x != 0.f) list[atomicAdd(&cnt, 1)] = 4 * b;
        if (v.y != 0.f) list[atomicAdd(&cnt, 1)] = 4 * b + 1;
        if (v.z != 0.f) list[atomicAdd(&cnt, 1)] = 4 * b + 2;
        if (v.w != 0.f) list[atomicAdd(&cnt, 1)] = 4 * b + 3;
    }
    __syncthreads();
    const int c = cnt;
    float s0 = 0.f, s1 = 0.f, s2 = 0.f, s3 = 0.f;
    float s4 = 0.f, s5 = 0.f, s6 = 0.f, s7 = 0.f;
    int j = 0;
    for (; j + 8 <= c; j += 8) {
        s0 += A[(size_t)list[j] * F + t];
        s1 += A[(size_t)list[j + 1] * F + t];
        s2 += A[(size_t)list[j + 2] * F + t];
        s3 += A[(size_t)list[j + 3] * F + t];
        s4 += A[(size_t)list[j + 4] * F + t];
        s5 += A[(size_t)list[j + 5] * F + t];
        s6 += A[(size_t)list[j + 6] * F + t];
        s7 += A[(size_t)list[j + 7] * F + t];
    }
    for (; j < c; ++j) s0 += A[(size_t)list[j] * F + t];
    const float mv = ((s0 + s1) + (s2 + s3)) + ((s4 + s5) + (s6 + s7));
    const float av = A[(size_t)a * F + t];
    Abf[(size_t)a * F + t] = __float2bfloat16(av);
    Mbf[(size_t)a * F + t] = __float2bfloat16(mv);

    float paa = av * av, pam = av * mv, pmm = mv * mv;
    #pragma unroll
    for (int o = 32; o > 0; o >>= 1) {
        paa += __shfl_down(paa, o);
        pam += __shfl_down(pam, o);
        pmm += __shfl_down(pmm, o);
    }
    __shared__ float s[3][4];
    const int wid = t >> 6;
    if ((t & 63) == 0) { s[0][wid] = paa; s[1][wid] = pam; s[2][wid] = pmm; }
    __syncthreads();
    if (t < P) {
        const float naa = s[0][0] + s[0][1] + s[0][2] + s[0][3];
        const float nam = s[1][0] + s[1][1] + s[1][2] + s[1][3];
        const float nmm = s[2][0] + s[2][1] + s[2][2] + s[2][3];
        const float Ti = Tt[t], ei = ee[t], ri = rr[t], Wi = Ww[t];
        const float wb = (1.f - ri) * Wi;
        const float n2 = ri * ri * naa + 2.f * ri * wb * nam + wb * wb * nmm;
        const float rn = rsqrtf(n2);
        const float p = persona[(size_t)(*times) * (size_t)N * P + (size_t)a * P + t];
        float4 q;
        q.x = ri * rn;                       // alpha
        q.y = wb * rn;                       // beta
        q.z = p;                             // p0
        q.w = p + (t == 0 ? 1.f : 0.f);      // p1 (i==0 init term)
        qtab[a * P + t] = q;                 // AoS by agent: personas contiguous
        if (a == 0) {
            const float invT = 1.f / (Ti + EPSV);
            const float sc = ei / (ei * __expf(invT) + EPSV);
            cst[2 * t] = invT * 1.4426950408889634f;   // k1 (log2 exponent scale)
            cst[2 * t + 1] = __log2f(sc);              // lsc (folded post-scale)
        }
    }
    if (a == 0 && t == 0) *ctr = GRIDSZ;  // work-stealing counter (stream-ordered)
}

// K1: persistent fused 4-Gram MFMA + dual-tile persona epilogue.
// 512 blocks x 8 waves; work-stealing over 64x64 triangle tiles.
// launch_bounds(512,6): cap VGPR at 85 -> 3 blocks/CU (6 waves/SIMD).
__global__ __launch_bounds__(512, 6) void gram_kernel(
    const __hip_bfloat16* __restrict__ Abf, const __hip_bfloat16* __restrict__ Mbf,
    const float4* __restrict__ qtab, const float* __restrict__ cst,
    int* __restrict__ ctr, float* __restrict__ out) {
    // [0,32768): 2 buffers x 4 panels x [64][32] bf16
    // [32768,37888): qrow (64 agents x 5 personas x float4); [37888,43008): qcol
    __shared__ __align__(16) char smem[43008];
    __shared__ int snext;

    const int t = threadIdx.x;
    const int lane = t & 63;
    const int w = t >> 6;          // 0..7
    const int wr = w >> 1;         // 0..3: 16-row strip
    const int wc = w & 1;          // 0..1: 32-col strip

    // staging geometry: wave w owns panel pn=w>>1 (0=rowA,1=rowM,2=colA,3=colM),
    // half hh=w&1; source column pre-swizzled (involution slot^((row>>1)&3)).
    const int sslot = (lane & 3) ^ ((lane >> 3) & 3);
    const int srowoff = (w & 1) * 32 + (lane >> 2);
    const int ldsp = (w >> 1) * 4096 + (w & 1) * 2048;
    const __hip_bfloat16* smat = ((w >> 1) & 1) ? Mbf : Abf;

    // fragment-read geometry (matching swizzle)
    const int frow = lane & 15;
    const int fg = lane >> 4;
    const int jr = fg << 2;
    const int rdslot = (fg ^ ((frow >> 1) & 3)) << 4;
    const int aoff = (wr * 16 + frow) * 64 + rdslot;
    const int coff0 = (wc * 32 + frow) * 64 + rdslot;
    const int coff1 = (wc * 32 + 16 + frow) * 64 + rdslot;

    const float4* qrow = (const float4*)(smem + 32768);
    const float4* qcol = (const float4*)(smem + 37888);

    int raw = blockIdx.x;
    while (raw < NTRI) {
        // XCD-chunked bijective swizzle (2080 % 8 == 0)
        const int bid = (raw & 7) * 260 + (raw >> 3);
        int bx = (int)((sqrtf(8.f * (float)bid + 1.f) - 1.f) * 0.5f);
        while ((bx + 1) * (bx + 2) / 2 <= bid) ++bx;
        while (bx * (bx + 1) / 2 > bid) --bx;
        const int by = bid - bx * (bx + 1) / 2;
        const int row0 = by << 6, col0 = bx << 6;

        const int sbase = (w < 4) ? row0 : col0;
        const __hip_bfloat16* psrc =
            smat + (size_t)(sbase + srowoff) * F + sslot * 8;

        #define STAGE(b, ks)  do {                                        \
            const char* lb_ = smem + (b) * 16384 + ldsp;                  \
            gload16(psrc + (ks), lb_);                                    \
            gload16(psrc + (ks) + 16 * F, lb_ + 1024);                    \
        } while (0)

        __syncthreads();  // all LDS reads of previous tile complete
        STAGE(0, 0);
        if (w == 0) {
            #pragma unroll
            for (int it = 0; it < 5; ++it)
                gload16(qtab + row0 * P + it * 64 + lane, smem + 32768 + it * 1024);
        } else if (w == 1) {
            #pragma unroll
            for (int it = 0; it < 5; ++it)
                gload16(qtab + col0 * P + it * 64 + lane, smem + 37888 + it * 1024);
        }
        if (t == 0) snext = atomicAdd(ctr, 1);
        __syncthreads();

        f32x4 acc[4][2];  // [gram AA,AM,MA,MM][n]
        #pragma unroll
        for (int g = 0; g < 4; ++g)
            #pragma unroll
            for (int n = 0; n < 2; ++n) acc[g][n] = (f32x4){0.f, 0.f, 0.f, 0.f};

        for (int s = 0; s < NSTEP; ++s) {
            const int b = s & 1;
            if (s + 1 < NSTEP) STAGE(b ^ 1, (s + 1) * BK);
            const char* base = smem + b * 16384;
            const bf16x8 aA = *(const bf16x8*)(base + aoff);
            const bf16x8 aM = *(const bf16x8*)(base + 4096 + aoff);
            const bf16x8 bA0 = *(const bf16x8*)(base + 8192 + coff0);
            const bf16x8 bA1 = *(const bf16x8*)(base + 8192 + coff1);
            const bf16x8 bM0 = *(const bf16x8*)(base + 12288 + coff0);
            const bf16x8 bM1 = *(const bf16x8*)(base + 12288 + coff1);
            acc[0][0] = mfma16(aA, bA0, acc[0][0]);
            acc[0][1] = mfma16(aA, bA1, acc[0][1]);
            acc[1][0] = mfma16(aA, bM0, acc[1][0]);
            acc[1][1] = mfma16(aA, bM1, acc[1][1]);
            acc[2][0] = mfma16(aM, bA0, acc[2][0]);
            acc[2][1] = mfma16(aM, bA1, acc[2][1]);
            acc[3][0] = mfma16(aM, bM0, acc[3][0]);
            acc[3][1] = mfma16(aM, bM1, acc[3][1]);
            if (s + 1 < NSTEP) __syncthreads();
            // no barrier after last step: epilogue only reads qtab LDS; panel
            // overwrite is behind the next tile's leading __syncthreads.
        }

        // Epilogue: g symmetric; out(r,c)=sum th*pc0*pr1, out(c,r)=sum th*pr0*pc1
        float o1[2][4], o2[2][4];  // [n][j]
        #pragma unroll
        for (int n = 0; n < 2; ++n)
            #pragma unroll
            for (int j = 0; j < 4; ++j) { o1[n][j] = 0.f; o2[n][j] = 0.f; }

        #pragma unroll
        for (int i = 0; i < P; ++i) {
            const float k1 = cst[2 * i], lsc = cst[2 * i + 1];
            float4 qc[2];
            #pragma unroll
            for (int n = 0; n < 2; ++n)
                qc[n] = qcol[(wc * 32 + n * 16 + frow) * P + i];
            #pragma unroll
            for (int j = 0; j < 4; ++j) {
                const float4 qr = qrow[(wr * 16 + jr + j) * P + i];
                #pragma unroll
                for (int n = 0; n < 2; ++n) {
                    const float h0 = qr.x * acc[0][n][j] + qr.y * acc[2][n][j];
                    const float h1 = qr.x * acc[1][n][j] + qr.y * acc[3][n][j];
                    const float g = h0 * qc[n].x + h1 * qc[n].y;
                    const float x = exp2f(fmaf(g, k1, lsc));
                    const float e2 = exp2f(x * 2.8853900817779268f);  // exp(2x)
                    const float th = 1.f - 2.f * __builtin_amdgcn_rcpf(e2 + 1.f);
                    o1[n][j] = fmaf(th * qc[n].z, qr.w, o1[n][j]);
                    o2[n][j] = fmaf(th * qr.z, qc[n].w, o2[n][j]);
                }
            }
        }

        // tile1 (row0, col0): coalesced stores (16 lanes x 4B per row segment)
        #pragma unroll
        for (int j = 0; j < 4; ++j) {
            const int gr = row0 + wr * 16 + jr + j;
            #pragma unroll
            for (int n = 0; n < 2; ++n) {
                const int gc = col0 + wc * 32 + n * 16 + frow;
                out[(size_t)gr * N + gc] = o1[n][j];
            }
        }
        // tile2 (col0, row0): direct transposed scalar stores (L2 write-merged;
        // verified twice: WRITE_SIZE stays at the 64MB ideal)
        if (by != bx) {
            #pragma unroll
            for (int j = 0; j < 4; ++j) {
                const int gr = row0 + wr * 16 + jr + j;
                #pragma unroll
                for (int n = 0; n < 2; ++n) {
                    const int gc = col0 + wc * 32 + n * 16 + frow;
                    out[(size_t)gc * N + gr] = o2[n][j];
                }
            }
        }
        raw = snext;  // uniform; next write is behind two barriers
        #undef STAGE
    }
}

extern "C" void kernel_launch(void* const* d_in, const int* in_sizes, int n_in,
                              void* d_out, int out_size, void* d_ws, size_t ws_size,
                              hipStream_t stream) {
    const float* A = (const float*)d_in[0];
    const float* E = (const float*)d_in[1];
    const float* persona = (const float*)d_in[2];
    const float* T = (const float*)d_in[3];
    const float* e = (const float*)d_in[4];
    const float* r = (const float*)d_in[5];
    const float* W = (const float*)d_in[6];
    const int* times = (const int*)d_in[7];
    float* out = (float*)d_out;

    char* ws = (char*)d_ws;
    __hip_bfloat16* Abf = (__hip_bfloat16*)ws;                    // 2 MB
    __hip_bfloat16* Mbf = (__hip_bfloat16*)(ws + (2 << 20));      // 2 MB
    float4* qtab = (float4*)(ws + (4 << 20));                     // 320 KB
    float* cst = (float*)(ws + (4 << 20) + P * N * 16);           // 40 B
    int* ctr = (int*)(ws + (4 << 20) + P * N * 16 + 64);          // 4 B

    prep_kernel<<<N, 256, 0, stream>>>(E, A, persona, T, e, r, W, times,
                                       Abf, Mbf, qtab, cst, ctr);
    gram_kernel<<<GRIDSZ, 512, 0, stream>>>(Abf, Mbf, qtab, cst, ctr, out);
}

// Round 11
// 227.874 us; speedup vs baseline: 1.4416x; 1.4416x over previous
//
#include <hip/hip_runtime.h>
#include <hip/hip_bf16.h>

#define N 4096
#define F 256
#define P 5
#define EPSV 1e-8f
#define BK 32
#define NSTEP (F / BK)  // 8
#define NTRI 2080       // 64*65/2 upper-triangle 64x64 tiles
#define GRIDSZ 512      // persistent blocks
#define DDEG 12         // polynomial degree for tanh(sc*exp(invT*g))
#define NC (DDEG + 1)   // 13 coefficients per persona

typedef __attribute__((ext_vector_type(8))) short bf16x8;
typedef __attribute__((ext_vector_type(4))) float f32x4;
typedef __attribute__((ext_vector_type(2))) float f32x2;

__device__ __forceinline__ f32x4 mfma16(bf16x8 a, bf16x8 b, f32x4 c) {
    return __builtin_amdgcn_mfma_f32_16x16x32_bf16(a, b, c, 0, 0, 0);
}

__device__ __forceinline__ void gload16(const void* src, const char* ldsdst) {
    __builtin_amdgcn_global_load_lds(
        (const __attribute__((address_space(1))) void*)src,
        (__attribute__((address_space(3))) void*)ldsdst, 16, 0, 0);
}

__device__ __forceinline__ f32x2 sp(float x) { return (f32x2){x, x}; }

// K0 (fused): msg = E @ A via sparse index compaction, norms, bf16 casts,
// SoA q-tables qsoa[i][field][agent] (field: alpha,beta,p0,p1), and a
// degree-12 on-device Chebyshev fit of f_i(g)=tanh(sc_i*exp(invT_i*g)).
__global__ __launch_bounds__(256, 8) void prep_kernel(
    const float* __restrict__ E, const float* __restrict__ A,
    const float* __restrict__ persona,
    const float* __restrict__ Tt, const float* __restrict__ ee,
    const float* __restrict__ rr, const float* __restrict__ Ww,
    const int* __restrict__ times,
    __hip_bfloat16* __restrict__ Abf, __hip_bfloat16* __restrict__ Mbf,
    float* __restrict__ qsoa, float* __restrict__ cstg, int* __restrict__ ctr) {
    __shared__ int cnt;
    __shared__ int list[1024];
    const int a = blockIdx.x;
    const int t = threadIdx.x;
    if (t == 0) cnt = 0;
    __syncthreads();
    const float4* erow = (const float4*)(E + (size_t)a * N);
    for (int b = t; b < N / 4; b += 256) {
        const float4 v = erow[b];
        if (v.x != 0.f) list[atomicAdd(&cnt, 1)] = 4 * b;
        if (v.y != 0.f) list[atomicAdd(&cnt, 1)] = 4 * b + 1;
        if (v.z != 0.f) list[atomicAdd(&cnt, 1)] = 4 * b + 2;
        if (v.w != 0.f) list[atomicAdd(&cnt, 1)] = 4 * b + 3;
    }
    __syncthreads();
    const int c = cnt;
    float s0 = 0.f, s1 = 0.f, s2 = 0.f, s3 = 0.f;
    float s4 = 0.f, s5 = 0.f, s6 = 0.f, s7 = 0.f;
    int j = 0;
    for (; j + 8 <= c; j += 8) {
        s0 += A[(size_t)list[j] * F + t];
        s1 += A[(size_t)list[j + 1] * F + t];
        s2 += A[(size_t)list[j + 2] * F + t];
        s3 += A[(size_t)list[j + 3] * F + t];
        s4 += A[(size_t)list[j + 4] * F + t];
        s5 += A[(size_t)list[j + 5] * F + t];
        s6 += A[(size_t)list[j + 6] * F + t];
        s7 += A[(size_t)list[j + 7] * F + t];
    }
    for (; j < c; ++j) s0 += A[(size_t)list[j] * F + t];
    const float mv = ((s0 + s1) + (s2 + s3)) + ((s4 + s5) + (s6 + s7));
    const float av = A[(size_t)a * F + t];
    Abf[(size_t)a * F + t] = __float2bfloat16(av);
    Mbf[(size_t)a * F + t] = __float2bfloat16(mv);

    float paa = av * av, pam = av * mv, pmm = mv * mv;
    #pragma unroll
    for (int o = 32; o > 0; o >>= 1) {
        paa += __shfl_down(paa, o);
        pam += __shfl_down(pam, o);
        pmm += __shfl_down(pmm, o);
    }
    __shared__ float s[3][4];
    const int wid = t >> 6;
    if ((t & 63) == 0) { s[0][wid] = paa; s[1][wid] = pam; s[2][wid] = pmm; }
    __syncthreads();
    if (t < P) {
        const float naa = s[0][0] + s[0][1] + s[0][2] + s[0][3];
        const float nam = s[1][0] + s[1][1] + s[1][2] + s[1][3];
        const float nmm = s[2][0] + s[2][1] + s[2][2] + s[2][3];
        const float Ti = Tt[t], ei = ee[t], ri = rr[t], Wi = Ww[t];
        const float wb = (1.f - ri) * Wi;
        const float n2 = ri * ri * naa + 2.f * ri * wb * nam + wb * wb * nmm;
        const float rn = rsqrtf(n2);
        const float p = persona[(size_t)(*times) * (size_t)N * P + (size_t)a * P + t];
        // SoA: qsoa[(i*4+field)*N + agent]; fields: 0=alpha,1=beta,2=p0,3=p1
        qsoa[(t * 4 + 0) * N + a] = ri * rn;
        qsoa[(t * 4 + 1) * N + a] = wb * rn;
        qsoa[(t * 4 + 2) * N + a] = p;
        qsoa[(t * 4 + 3) * N + a] = p + (t == 0 ? 1.f : 0.f);
        if (a == 0) {
            // fit monomial (in g) approx of f(g)=tanh(sc*exp(invT*g)) on [-1.05,1.05]
            const double kk = 1.0 / ((double)Ti + 1e-8);
            const double ed = (double)ei;
            const double scd = ed / (ed * exp(kk) + 1e-8);
            double ch[NC];
            for (int j2 = 0; j2 < NC; ++j2) ch[j2] = 0.0;
            for (int m = 0; m < 32; ++m) {
                const double th = 3.14159265358979323846 * (m + 0.5) / 32.0;
                const double fm = tanh(scd * exp(kk * 1.05 * cos(th)));
                for (int j2 = 0; j2 < NC; ++j2) ch[j2] += fm * cos(j2 * th);
            }
            for (int j2 = 0; j2 < NC; ++j2) ch[j2] *= (j2 == 0 ? 1.0 : 2.0) / 32.0;
            // Chebyshev T_j(s), s=g/1.05 -> monomial coefficients in g
            double mono[NC], Tp[NC], Tc[NC], Tn[NC];
            const double is = 1.0 / 1.05;
            for (int k2 = 0; k2 < NC; ++k2) { mono[k2] = 0; Tp[k2] = 0; Tc[k2] = 0; }
            Tp[0] = 1.0;
            Tc[1] = is;
            for (int k2 = 0; k2 < NC; ++k2) mono[k2] += ch[0] * Tp[k2] + ch[1] * Tc[k2];
            for (int j2 = 2; j2 < NC; ++j2) {
                for (int k2 = 0; k2 < NC; ++k2)
                    Tn[k2] = 2.0 * is * (k2 ? Tc[k2 - 1] : 0.0) - Tp[k2];
                for (int k2 = 0; k2 < NC; ++k2) mono[k2] += ch[j2] * Tn[k2];
                for (int k2 = 0; k2 < NC; ++k2) { Tp[k2] = Tc[k2]; Tc[k2] = Tn[k2]; }
            }
            for (int k2 = 0; k2 < NC; ++k2) cstg[t * NC + k2] = (float)mono[k2];
        }
    }
    if (a == 0 && t == 0) *ctr = GRIDSZ;  // work-stealing counter (stream-ordered)
}

// K1: persistent fused 4-Gram MFMA + polynomial persona epilogue (no trans).
// 512 blocks x 8 waves; work-stealing over 64x64 triangle tiles.
// Epilogue on float2 j-pairs -> packed fp32 (v_pk_fma) candidates.
__global__ __launch_bounds__(512) void gram_kernel(
    const __hip_bfloat16* __restrict__ Abf, const __hip_bfloat16* __restrict__ Mbf,
    const float* __restrict__ qsoa, const float* __restrict__ cstg,
    int* __restrict__ ctr, float* __restrict__ out) {
    // [0,32768): 2 buffers x 4 panels x [64][32] bf16
    // [32768,37888): qrow SoA (5 i x 4 fields x 64 rows floats)
    // [37888,43008): qcol SoA;  [43008,43280): 68 poly coeffs
    __shared__ __align__(16) char smem[43280];
    __shared__ int snext;

    const int t = threadIdx.x;
    const int lane = t & 63;
    const int w = t >> 6;          // 0..7
    const int wr = w >> 1;         // 0..3: 16-row strip
    const int wc = w & 1;          // 0..1: 32-col strip

    // staging geometry: wave w owns panel pn=w>>1 (0=rowA,1=rowM,2=colA,3=colM),
    // half hh=w&1; source column pre-swizzled (involution slot^((row>>1)&3)).
    const int sslot = (lane & 3) ^ ((lane >> 3) & 3);
    const int srowoff = (w & 1) * 32 + (lane >> 2);
    const int ldsp = (w >> 1) * 4096 + (w & 1) * 2048;
    const __hip_bfloat16* smat = ((w >> 1) & 1) ? Mbf : Abf;

    // fragment-read geometry (matching swizzle)
    const int frow = lane & 15;
    const int fg = lane >> 4;
    const int jr = fg << 2;
    const int rdslot = (fg ^ ((frow >> 1) & 3)) << 4;
    const int aoff = (wr * 16 + frow) * 64 + rdslot;
    const int coff0 = (wc * 32 + frow) * 64 + rdslot;
    const int coff1 = (wc * 32 + 16 + frow) * 64 + rdslot;

    const float* qlr = (const float*)(smem + 32768);
    const float* qlc = (const float*)(smem + 37888);
    const float* cfs = (const float*)(smem + 43008);

    int raw = blockIdx.x;
    while (raw < NTRI) {
        // XCD-chunked bijective swizzle (2080 % 8 == 0)
        const int bid = (raw & 7) * 260 + (raw >> 3);
        int bx = (int)((sqrtf(8.f * (float)bid + 1.f) - 1.f) * 0.5f);
        while ((bx + 1) * (bx + 2) / 2 <= bid) ++bx;
        while (bx * (bx + 1) / 2 > bid) --bx;
        const int by = bid - bx * (bx + 1) / 2;
        const int row0 = by << 6, col0 = bx << 6;

        const int sbase = (w < 4) ? row0 : col0;
        const __hip_bfloat16* psrc =
            smat + (size_t)(sbase + srowoff) * F + sslot * 8;

        #define STAGE(b, ks)  do {                                        \
            const char* lb_ = smem + (b) * 16384 + ldsp;                  \
            gload16(psrc + (ks), lb_);                                    \
            gload16(psrc + (ks) + 16 * F, lb_ + 1024);                    \
        } while (0)

        __syncthreads();  // all LDS reads of previous tile complete
        STAGE(0, 0);
        // q SoA slices -> LDS. Per call: 4 combos (i*4+field), lane l covers
        // combo l>>4, agents (l&15)*4 .. +3 (16B). LDS linear [combo][256B].
        if (w == 0) {
            #pragma unroll
            for (int it = 0; it < 5; ++it)
                gload16(qsoa + (it * 4 + (lane >> 4)) * N + row0 + (lane & 15) * 4,
                        smem + 32768 + it * 1024);
        } else if (w == 1) {
            #pragma unroll
            for (int it = 0; it < 5; ++it)
                gload16(qsoa + (it * 4 + (lane >> 4)) * N + col0 + (lane & 15) * 4,
                        smem + 37888 + it * 1024);
        } else if (w == 2) {
            if (lane < 17) gload16(cstg + lane * 4, smem + 43008);
        }
        if (t == 0) snext = atomicAdd(ctr, 1);
        __syncthreads();

        f32x4 acc[4][2];  // [gram AA,AM,MA,MM][n]
        #pragma unroll
        for (int g = 0; g < 4; ++g)
            #pragma unroll
            for (int n = 0; n < 2; ++n) acc[g][n] = (f32x4){0.f, 0.f, 0.f, 0.f};

        for (int s = 0; s < NSTEP; ++s) {
            const int b = s & 1;
            if (s + 1 < NSTEP) STAGE(b ^ 1, (s + 1) * BK);
            const char* base = smem + b * 16384;
            const bf16x8 aA = *(const bf16x8*)(base + aoff);
            const bf16x8 aM = *(const bf16x8*)(base + 4096 + aoff);
            const bf16x8 bA0 = *(const bf16x8*)(base + 8192 + coff0);
            const bf16x8 bA1 = *(const bf16x8*)(base + 8192 + coff1);
            const bf16x8 bM0 = *(const bf16x8*)(base + 12288 + coff0);
            const bf16x8 bM1 = *(const bf16x8*)(base + 12288 + coff1);
            acc[0][0] = mfma16(aA, bA0, acc[0][0]);
            acc[0][1] = mfma16(aA, bA1, acc[0][1]);
            acc[1][0] = mfma16(aA, bM0, acc[1][0]);
            acc[1][1] = mfma16(aA, bM1, acc[1][1]);
            acc[2][0] = mfma16(aM, bA0, acc[2][0]);
            acc[2][1] = mfma16(aM, bA1, acc[2][1]);
            acc[3][0] = mfma16(aM, bM0, acc[3][0]);
            acc[3][1] = mfma16(aM, bM1, acc[3][1]);
            if (s + 1 < NSTEP) __syncthreads();
        }

        // Polynomial epilogue on float2 j-pairs (no transcendentals):
        // f_i(g) = poly(g); out(r,c)=sum f*p0(c)*p1(r); out(c,r)=sum f*p0(r)*p1(c)
        f32x2 o1[2][2], o2[2][2];  // [n][jpair]
        #pragma unroll
        for (int n = 0; n < 2; ++n)
            #pragma unroll
            for (int jp = 0; jp < 2; ++jp) { o1[n][jp] = sp(0.f); o2[n][jp] = sp(0.f); }

        #pragma unroll
        for (int i = 0; i < P; ++i) {
            const int ib = i * 256;  // (i*4+field)*64
            float cf[NC];
            #pragma unroll
            for (int k = 0; k < NC; ++k) cf[k] = cfs[i * NC + k];
            float cA[2], cB[2], cP0[2], cP1[2];
            #pragma unroll
            for (int n = 0; n < 2; ++n) {
                const int cr = wc * 32 + n * 16 + frow;
                cA[n]  = qlc[ib + cr];
                cB[n]  = qlc[ib + 64 + cr];
                cP0[n] = qlc[ib + 128 + cr];
                cP1[n] = qlc[ib + 192 + cr];
            }
            #pragma unroll
            for (int jp = 0; jp < 2; ++jp) {
                const int rrw = wr * 16 + jr + jp * 2;
                const f32x2 rA  = *(const f32x2*)&qlr[ib + rrw];
                const f32x2 rB  = *(const f32x2*)&qlr[ib + 64 + rrw];
                const f32x2 rP0 = *(const f32x2*)&qlr[ib + 128 + rrw];
                const f32x2 rP1 = *(const f32x2*)&qlr[ib + 192 + rrw];
                #pragma unroll
                for (int n = 0; n < 2; ++n) {
                    const f32x2 aAA = (f32x2){acc[0][n][2 * jp], acc[0][n][2 * jp + 1]};
                    const f32x2 aAM = (f32x2){acc[1][n][2 * jp], acc[1][n][2 * jp + 1]};
                    const f32x2 aMA = (f32x2){acc[2][n][2 * jp], acc[2][n][2 * jp + 1]};
                    const f32x2 aMM = (f32x2){acc[3][n][2 * jp], acc[3][n][2 * jp + 1]};
                    const f32x2 h0 = rA * aAA + rB * aMA;
                    const f32x2 h1 = rA * aAM + rB * aMM;
                    const f32x2 g2 = h0 * sp(cA[n]) + h1 * sp(cB[n]);
                    f32x2 f2 = sp(cf[DDEG]);
                    #pragma unroll
                    for (int k = DDEG - 1; k >= 0; --k) f2 = f2 * g2 + sp(cf[k]);
                    o1[n][jp] += (f2 * rP1) * sp(cP0[n]);
                    o2[n][jp] += (f2 * rP0) * sp(cP1[n]);
                }
            }
        }

        // tile1 (row0, col0): coalesced stores
        #pragma unroll
        for (int jp = 0; jp < 2; ++jp)
            #pragma unroll
            for (int cc = 0; cc < 2; ++cc) {
                const int gr = row0 + wr * 16 + jr + jp * 2 + cc;
                #pragma unroll
                for (int n = 0; n < 2; ++n) {
                    const int gc = col0 + wc * 32 + n * 16 + frow;
                    out[(size_t)gr * N + gc] = o1[n][jp][cc];
                }
            }
        // tile2 (col0, row0): direct transposed scalar stores (L2 write-merged)
        if (by != bx) {
            #pragma unroll
            for (int jp = 0; jp < 2; ++jp)
                #pragma unroll
                for (int cc = 0; cc < 2; ++cc) {
                    const int gr = row0 + wr * 16 + jr + jp * 2 + cc;
                    #pragma unroll
                    for (int n = 0; n < 2; ++n) {
                        const int gc = col0 + wc * 32 + n * 16 + frow;
                        out[(size_t)gc * N + gr] = o2[n][jp][cc];
                    }
                }
        }
        raw = snext;  // uniform; next write is behind two barriers
        #undef STAGE
    }
}

extern "C" void kernel_launch(void* const* d_in, const int* in_sizes, int n_in,
                              void* d_out, int out_size, void* d_ws, size_t ws_size,
                              hipStream_t stream) {
    const float* A = (const float*)d_in[0];
    const float* E = (const float*)d_in[1];
    const float* persona = (const float*)d_in[2];
    const float* T = (const float*)d_in[3];
    const float* e = (const float*)d_in[4];
    const float* r = (const float*)d_in[5];
    const float* W = (const float*)d_in[6];
    const int* times = (const int*)d_in[7];
    float* out = (float*)d_out;

    char* ws = (char*)d_ws;
    __hip_bfloat16* Abf = (__hip_bfloat16*)ws;                    // 2 MB
    __hip_bfloat16* Mbf = (__hip_bfloat16*)(ws + (2 << 20));      // 2 MB
    float* qsoa = (float*)(ws + (4 << 20));                       // 320 KB SoA
    float* cstg = (float*)(ws + (4 << 20) + 5 * 4 * N * 4);       // 272 B coeffs
    int* ctr = (int*)(ws + (4 << 20) + 5 * 4 * N * 4 + 512);      // 4 B

    prep_kernel<<<N, 256, 0, stream>>>(E, A, persona, T, e, r, W, times,
                                       Abf, Mbf, qsoa, cstg, ctr);
    gram_kernel<<<GRIDSZ, 512, 0, stream>>>(Abf, Mbf, qsoa, cstg, ctr, out);
}

// Round 12
// 89.088 us; speedup vs baseline: 3.6874x; 2.5578x over previous
//
#include <hip/hip_runtime.h>
#include <hip/hip_bf16.h>

#define N 4096
#define F 256
#define P 5
#define EPSV 1e-8f
#define BK 32
#define NSTEP (F / BK)  // 8
#define NTRI 2080       // 64*65/2 upper-triangle 64x64 tiles
#define GRIDSZ 512      // persistent blocks
#define DDEG 12         // polynomial degree for tanh(sc*exp(invT*g))
#define NC (DDEG + 1)   // 13 coefficients per persona

typedef __attribute__((ext_vector_type(8))) short bf16x8;
typedef __attribute__((ext_vector_type(4))) float f32x4;
typedef __attribute__((ext_vector_type(2))) float f32x2;

__device__ __forceinline__ f32x4 mfma16(bf16x8 a, bf16x8 b, f32x4 c) {
    return __builtin_amdgcn_mfma_f32_16x16x32_bf16(a, b, c, 0, 0, 0);
}

__device__ __forceinline__ void gload16(const void* src, const char* ldsdst) {
    __builtin_amdgcn_global_load_lds(
        (const __attribute__((address_space(1))) void*)src,
        (__attribute__((address_space(3))) void*)ldsdst, 16, 0, 0);
}

__device__ __forceinline__ f32x2 sp(float x) { return (f32x2){x, x}; }

// K0 (fused): msg = E @ A via sparse index compaction, norms, bf16 casts,
// SoA q-tables qsoa[i][field][agent], and a degree-12 Chebyshev fit of
// f_i(g)=tanh(sc_i*exp(invT_i*g)) using ONLY float hardware transcendentals
// (double tanh/exp/cos were ~900cyc each and made block 0 take 188us).
__global__ __launch_bounds__(256, 8) void prep_kernel(
    const float* __restrict__ E, const float* __restrict__ A,
    const float* __restrict__ persona,
    const float* __restrict__ Tt, const float* __restrict__ ee,
    const float* __restrict__ rr, const float* __restrict__ Ww,
    const int* __restrict__ times,
    __hip_bfloat16* __restrict__ Abf, __hip_bfloat16* __restrict__ Mbf,
    float* __restrict__ qsoa, float* __restrict__ cstg, int* __restrict__ ctr) {
    __shared__ int cnt;
    __shared__ int list[1024];
    const int a = blockIdx.x;
    const int t = threadIdx.x;
    if (t == 0) cnt = 0;
    __syncthreads();
    const float4* erow = (const float4*)(E + (size_t)a * N);
    for (int b = t; b < N / 4; b += 256) {
        const float4 v = erow[b];
        if (v.x != 0.f) list[atomicAdd(&cnt, 1)] = 4 * b;
        if (v.y != 0.f) list[atomicAdd(&cnt, 1)] = 4 * b + 1;
        if (v.z != 0.f) list[atomicAdd(&cnt, 1)] = 4 * b + 2;
        if (v.w != 0.f) list[atomicAdd(&cnt, 1)] = 4 * b + 3;
    }
    __syncthreads();
    const int c = cnt;
    float s0 = 0.f, s1 = 0.f, s2 = 0.f, s3 = 0.f;
    float s4 = 0.f, s5 = 0.f, s6 = 0.f, s7 = 0.f;
    int j = 0;
    for (; j + 8 <= c; j += 8) {
        s0 += A[(size_t)list[j] * F + t];
        s1 += A[(size_t)list[j + 1] * F + t];
        s2 += A[(size_t)list[j + 2] * F + t];
        s3 += A[(size_t)list[j + 3] * F + t];
        s4 += A[(size_t)list[j + 4] * F + t];
        s5 += A[(size_t)list[j + 5] * F + t];
        s6 += A[(size_t)list[j + 6] * F + t];
        s7 += A[(size_t)list[j + 7] * F + t];
    }
    for (; j < c; ++j) s0 += A[(size_t)list[j] * F + t];
    const float mv = ((s0 + s1) + (s2 + s3)) + ((s4 + s5) + (s6 + s7));
    const float av = A[(size_t)a * F + t];
    Abf[(size_t)a * F + t] = __float2bfloat16(av);
    Mbf[(size_t)a * F + t] = __float2bfloat16(mv);

    float paa = av * av, pam = av * mv, pmm = mv * mv;
    #pragma unroll
    for (int o = 32; o > 0; o >>= 1) {
        paa += __shfl_down(paa, o);
        pam += __shfl_down(pam, o);
        pmm += __shfl_down(pmm, o);
    }
    __shared__ float s[3][4];
    const int wid = t >> 6;
    if ((t & 63) == 0) { s[0][wid] = paa; s[1][wid] = pam; s[2][wid] = pmm; }
    __syncthreads();
    if (t < P) {
        const float naa = s[0][0] + s[0][1] + s[0][2] + s[0][3];
        const float nam = s[1][0] + s[1][1] + s[1][2] + s[1][3];
        const float nmm = s[2][0] + s[2][1] + s[2][2] + s[2][3];
        const float Ti = Tt[t], ei = ee[t], ri = rr[t], Wi = Ww[t];
        const float wb = (1.f - ri) * Wi;
        const float n2 = ri * ri * naa + 2.f * ri * wb * nam + wb * wb * nmm;
        const float rn = rsqrtf(n2);
        const float p = persona[(size_t)(*times) * (size_t)N * P + (size_t)a * P + t];
        // SoA: qsoa[(i*4+field)*N + agent]; fields: 0=alpha,1=beta,2=p0,3=p1
        qsoa[(t * 4 + 0) * N + a] = ri * rn;
        qsoa[(t * 4 + 1) * N + a] = wb * rn;
        qsoa[(t * 4 + 2) * N + a] = p;
        qsoa[(t * 4 + 3) * N + a] = p + (t == 0 ? 1.f : 0.f);
        if (a == 0) {
            // fit monomial approx of f(g)=tanh(sc*exp(invT*g)) on [-1.05,1.05]
            const float kk = 1.f / (Ti + EPSV);
            const float scf = ei / (ei * __expf(kk) + EPSV);
            float ch[NC];
            #pragma unroll
            for (int j2 = 0; j2 < NC; ++j2) ch[j2] = 0.f;
            for (int m = 0; m < 32; ++m) {
                const float th = 3.14159265358979323846f * (m + 0.5f) / 32.f;
                const float c1 = __cosf(th);
                const float x = scf * __expf(kk * 1.05f * c1);
                const float e2 = __expf(2.f * x);
                const float fm = 1.f - 2.f / (e2 + 1.f);   // tanh(x)
                // cos(j*th) by recurrence (no large-arg trig)
                float cjm1 = 1.f, cj = c1;
                ch[0] += fm;
                ch[1] += fm * c1;
                #pragma unroll
                for (int j2 = 2; j2 < NC; ++j2) {
                    const float cn = 2.f * c1 * cj - cjm1;
                    ch[j2] += fm * cn;
                    cjm1 = cj;
                    cj = cn;
                }
            }
            #pragma unroll
            for (int j2 = 0; j2 < NC; ++j2) ch[j2] *= (j2 == 0 ? 1.f : 2.f) / 32.f;
            // Chebyshev T_j(g/1.05) -> monomial coefficients in g (float, unrolled)
            float mono[NC], Tp[NC], Tc[NC], Tn[NC];
            const float is = 1.f / 1.05f;
            #pragma unroll
            for (int k2 = 0; k2 < NC; ++k2) {
                mono[k2] = 0.f; Tp[k2] = 0.f; Tc[k2] = 0.f; Tn[k2] = 0.f;
            }
            Tp[0] = 1.f;
            Tc[1] = is;
            #pragma unroll
            for (int k2 = 0; k2 < NC; ++k2) mono[k2] += ch[0] * Tp[k2] + ch[1] * Tc[k2];
            for (int j2 = 2; j2 < NC; ++j2) {
                #pragma unroll
                for (int k2 = 0; k2 < NC; ++k2)
                    Tn[k2] = 2.f * is * (k2 ? Tc[k2 - 1] : 0.f) - Tp[k2];
                #pragma unroll
                for (int k2 = 0; k2 < NC; ++k2) mono[k2] += ch[j2] * Tn[k2];
                #pragma unroll
                for (int k2 = 0; k2 < NC; ++k2) { Tp[k2] = Tc[k2]; Tc[k2] = Tn[k2]; }
            }
            #pragma unroll
            for (int k2 = 0; k2 < NC; ++k2) cstg[t * NC + k2] = mono[k2];
        }
    }
    if (a == 0 && t == 0) *ctr = GRIDSZ;  // work-stealing counter (stream-ordered)
}

// K1: persistent fused 4-Gram MFMA + polynomial persona epilogue (no trans).
// 512 blocks x 8 waves; work-stealing over 64x64 triangle tiles.
__global__ __launch_bounds__(512) void gram_kernel(
    const __hip_bfloat16* __restrict__ Abf, const __hip_bfloat16* __restrict__ Mbf,
    const float* __restrict__ qsoa, const float* __restrict__ cstg,
    int* __restrict__ ctr, float* __restrict__ out) {
    // [0,32768): 2 buffers x 4 panels x [64][32] bf16
    // [32768,37888): qrow SoA (5 i x 4 fields x 64 rows floats)
    // [37888,43008): qcol SoA;  [43008,43280): 68 poly coeffs
    __shared__ __align__(16) char smem[43280];
    __shared__ int snext;

    const int t = threadIdx.x;
    const int lane = t & 63;
    const int w = t >> 6;          // 0..7
    const int wr = w >> 1;         // 0..3: 16-row strip
    const int wc = w & 1;          // 0..1: 32-col strip

    // staging geometry: wave w owns panel pn=w>>1 (0=rowA,1=rowM,2=colA,3=colM),
    // half hh=w&1; source column pre-swizzled (involution slot^((row>>1)&3)).
    const int sslot = (lane & 3) ^ ((lane >> 3) & 3);
    const int srowoff = (w & 1) * 32 + (lane >> 2);
    const int ldsp = (w >> 1) * 4096 + (w & 1) * 2048;
    const __hip_bfloat16* smat = ((w >> 1) & 1) ? Mbf : Abf;

    // fragment-read geometry (matching swizzle)
    const int frow = lane & 15;
    const int fg = lane >> 4;
    const int jr = fg << 2;
    const int rdslot = (fg ^ ((frow >> 1) & 3)) << 4;
    const int aoff = (wr * 16 + frow) * 64 + rdslot;
    const int coff0 = (wc * 32 + frow) * 64 + rdslot;
    const int coff1 = (wc * 32 + 16 + frow) * 64 + rdslot;

    const float* qlr = (const float*)(smem + 32768);
    const float* qlc = (const float*)(smem + 37888);
    const float* cfs = (const float*)(smem + 43008);

    int raw = blockIdx.x;
    while (raw < NTRI) {
        // XCD-chunked bijective swizzle (2080 % 8 == 0)
        const int bid = (raw & 7) * 260 + (raw >> 3);
        int bx = (int)((sqrtf(8.f * (float)bid + 1.f) - 1.f) * 0.5f);
        while ((bx + 1) * (bx + 2) / 2 <= bid) ++bx;
        while (bx * (bx + 1) / 2 > bid) --bx;
        const int by = bid - bx * (bx + 1) / 2;
        const int row0 = by << 6, col0 = bx << 6;

        const int sbase = (w < 4) ? row0 : col0;
        const __hip_bfloat16* psrc =
            smat + (size_t)(sbase + srowoff) * F + sslot * 8;

        #define STAGE(b, ks)  do {                                        \
            const char* lb_ = smem + (b) * 16384 + ldsp;                  \
            gload16(psrc + (ks), lb_);                                    \
            gload16(psrc + (ks) + 16 * F, lb_ + 1024);                    \
        } while (0)

        __syncthreads();  // all LDS reads of previous tile complete
        STAGE(0, 0);
        // q SoA slices -> LDS. Per call: 4 combos (i*4+field), lane l covers
        // combo l>>4, agents (l&15)*4 .. +3 (16B). LDS linear [combo][256B].
        if (w == 0) {
            #pragma unroll
            for (int it = 0; it < 5; ++it)
                gload16(qsoa + (it * 4 + (lane >> 4)) * N + row0 + (lane & 15) * 4,
                        smem + 32768 + it * 1024);
        } else if (w == 1) {
            #pragma unroll
            for (int it = 0; it < 5; ++it)
                gload16(qsoa + (it * 4 + (lane >> 4)) * N + col0 + (lane & 15) * 4,
                        smem + 37888 + it * 1024);
        } else if (w == 2) {
            if (lane < 17) gload16(cstg + lane * 4, smem + 43008);
        }
        if (t == 0) snext = atomicAdd(ctr, 1);
        __syncthreads();

        f32x4 acc[4][2];  // [gram AA,AM,MA,MM][n]
        #pragma unroll
        for (int g = 0; g < 4; ++g)
            #pragma unroll
            for (int n = 0; n < 2; ++n) acc[g][n] = (f32x4){0.f, 0.f, 0.f, 0.f};

        for (int s = 0; s < NSTEP; ++s) {
            const int b = s & 1;
            if (s + 1 < NSTEP) STAGE(b ^ 1, (s + 1) * BK);
            const char* base = smem + b * 16384;
            const bf16x8 aA = *(const bf16x8*)(base + aoff);
            const bf16x8 aM = *(const bf16x8*)(base + 4096 + aoff);
            const bf16x8 bA0 = *(const bf16x8*)(base + 8192 + coff0);
            const bf16x8 bA1 = *(const bf16x8*)(base + 8192 + coff1);
            const bf16x8 bM0 = *(const bf16x8*)(base + 12288 + coff0);
            const bf16x8 bM1 = *(const bf16x8*)(base + 12288 + coff1);
            acc[0][0] = mfma16(aA, bA0, acc[0][0]);
            acc[0][1] = mfma16(aA, bA1, acc[0][1]);
            acc[1][0] = mfma16(aA, bM0, acc[1][0]);
            acc[1][1] = mfma16(aA, bM1, acc[1][1]);
            acc[2][0] = mfma16(aM, bA0, acc[2][0]);
            acc[2][1] = mfma16(aM, bA1, acc[2][1]);
            acc[3][0] = mfma16(aM, bM0, acc[3][0]);
            acc[3][1] = mfma16(aM, bM1, acc[3][1]);
            if (s + 1 < NSTEP) __syncthreads();
        }

        // Polynomial epilogue on float2 j-pairs (no transcendentals):
        // f_i(g) = poly(g); out(r,c)=sum f*p0(c)*p1(r); out(c,r)=sum f*p0(r)*p1(c)
        f32x2 o1[2][2], o2[2][2];  // [n][jpair]
        #pragma unroll
        for (int n = 0; n < 2; ++n)
            #pragma unroll
            for (int jp = 0; jp < 2; ++jp) { o1[n][jp] = sp(0.f); o2[n][jp] = sp(0.f); }

        #pragma unroll
        for (int i = 0; i < P; ++i) {
            const int ib = i * 256;  // (i*4+field)*64
            float cf[NC];
            #pragma unroll
            for (int k = 0; k < NC; ++k) cf[k] = cfs[i * NC + k];
            float cA[2], cB[2], cP0[2], cP1[2];
            #pragma unroll
            for (int n = 0; n < 2; ++n) {
                const int cr = wc * 32 + n * 16 + frow;
                cA[n]  = qlc[ib + cr];
                cB[n]  = qlc[ib + 64 + cr];
                cP0[n] = qlc[ib + 128 + cr];
                cP1[n] = qlc[ib + 192 + cr];
            }
            #pragma unroll
            for (int jp = 0; jp < 2; ++jp) {
                const int rrw = wr * 16 + jr + jp * 2;
                const f32x2 rA  = *(const f32x2*)&qlr[ib + rrw];
                const f32x2 rB  = *(const f32x2*)&qlr[ib + 64 + rrw];
                const f32x2 rP0 = *(const f32x2*)&qlr[ib + 128 + rrw];
                const f32x2 rP1 = *(const f32x2*)&qlr[ib + 192 + rrw];
                #pragma unroll
                for (int n = 0; n < 2; ++n) {
                    const f32x2 aAA = (f32x2){acc[0][n][2 * jp], acc[0][n][2 * jp + 1]};
                    const f32x2 aAM = (f32x2){acc[1][n][2 * jp], acc[1][n][2 * jp + 1]};
                    const f32x2 aMA = (f32x2){acc[2][n][2 * jp], acc[2][n][2 * jp + 1]};
                    const f32x2 aMM = (f32x2){acc[3][n][2 * jp], acc[3][n][2 * jp + 1]};
                    const f32x2 h0 = rA * aAA + rB * aMA;
                    const f32x2 h1 = rA * aAM + rB * aMM;
                    const f32x2 g2 = h0 * sp(cA[n]) + h1 * sp(cB[n]);
                    f32x2 f2 = sp(cf[DDEG]);
                    #pragma unroll
                    for (int k = DDEG - 1; k >= 0; --k) f2 = f2 * g2 + sp(cf[k]);
                    o1[n][jp] += (f2 * rP1) * sp(cP0[n]);
                    o2[n][jp] += (f2 * rP0) * sp(cP1[n]);
                }
            }
        }

        // tile1 (row0, col0): coalesced stores
        #pragma unroll
        for (int jp = 0; jp < 2; ++jp)
            #pragma unroll
            for (int cc = 0; cc < 2; ++cc) {
                const int gr = row0 + wr * 16 + jr + jp * 2 + cc;
                #pragma unroll
                for (int n = 0; n < 2; ++n) {
                    const int gc = col0 + wc * 32 + n * 16 + frow;
                    out[(size_t)gr * N + gc] = o1[n][jp][cc];
                }
            }
        // tile2 (col0, row0): direct transposed scalar stores (L2 write-merged)
        if (by != bx) {
            #pragma unroll
            for (int jp = 0; jp < 2; ++jp)
                #pragma unroll
                for (int cc = 0; cc < 2; ++cc) {
                    const int gr = row0 + wr * 16 + jr + jp * 2 + cc;
                    #pragma unroll
                    for (int n = 0; n < 2; ++n) {
                        const int gc = col0 + wc * 32 + n * 16 + frow;
                        out[(size_t)gc * N + gr] = o2[n][jp][cc];
                    }
                }
        }
        raw = snext;  // uniform; next write is behind two barriers
        #undef STAGE
    }
}

extern "C" void kernel_launch(void* const* d_in, const int* in_sizes, int n_in,
                              void* d_out, int out_size, void* d_ws, size_t ws_size,
                              hipStream_t stream) {
    const float* A = (const float*)d_in[0];
    const float* E = (const float*)d_in[1];
    const float* persona = (const float*)d_in[2];
    const float* T = (const float*)d_in[3];
    const float* e = (const float*)d_in[4];
    const float* r = (const float*)d_in[5];
    const float* W = (const float*)d_in[6];
    const int* times = (const int*)d_in[7];
    float* out = (float*)d_out;

    char* ws = (char*)d_ws;
    __hip_bfloat16* Abf = (__hip_bfloat16*)ws;                    // 2 MB
    __hip_bfloat16* Mbf = (__hip_bfloat16*)(ws + (2 << 20));      // 2 MB
    float* qsoa = (float*)(ws + (4 << 20));                       // 320 KB SoA
    float* cstg = (float*)(ws + (4 << 20) + 5 * 4 * N * 4);       // 272 B coeffs
    int* ctr = (int*)(ws + (4 << 20) + 5 * 4 * N * 4 + 512);      // 4 B

    prep_kernel<<<N, 256, 0, stream>>>(E, A, persona, T, e, r, W, times,
                                       Abf, Mbf, qsoa, cstg, ctr);
    gram_kernel<<<GRIDSZ, 512, 0, stream>>>(Abf, Mbf, qsoa, cstg, ctr, out);
}